// Round 1
// baseline (109.833 us; speedup 1.0000x reference)
//
#include <hip/hip_runtime.h>

#define N_  128
#define C_  256
#define T_  48
#define V_  25
#define CR_ 16

// Rows = N*C*T = 1,572,864 rows of V=25 contiguous floats.
// K1: xbar[row] = mean_v x[row*25+v]. 256 rows per block (6400 floats, contiguous, 16B aligned).
__global__ __launch_bounds__(256) void k_rowmean(const float* __restrict__ x,
                                                 float* __restrict__ xbar) {
    __shared__ float xs[6400];
    const int tid = threadIdx.x;
    const float4* x4 = (const float4*)x;
    const long long base4 = (long long)blockIdx.x * 1600;
    #pragma unroll
    for (int k = 0; k < 7; ++k) {
        int i4 = k * 256 + tid;
        if (i4 < 1600) ((float4*)xs)[i4] = x4[base4 + i4];
    }
    __syncthreads();
    float s = 0.f;
    #pragma unroll
    for (int v = 0; v < 25; ++v) s += xs[tid * 25 + v];  // stride 25: conflict-free
    xbar[(long long)blockIdx.x * 256 + tid] = s * (1.f / 25.f);
}

// K2: per (n, segment-of-3): gate[n,c,t0..t0+2] from xbar[n,:,t0..t0+2].
__global__ __launch_bounds__(256) void k_gate(const float* __restrict__ xbar,
    const float* __restrict__ wsq, const float* __restrict__ bsq,
    const float* __restrict__ gamma, const float* __restrict__ beta,
    const float* __restrict__ rmean, const float* __restrict__ rvar,
    const float* __restrict__ wc1, const float* __restrict__ bc1,
    const float* __restrict__ wex, const float* __restrict__ bex,
    float* __restrict__ gate) {
    __shared__ float xb[C_ * 3];   // [c][tt]
    __shared__ float ybn[48];      // [tt][r]
    __shared__ float y1[48];       // [tt][s]
    __shared__ float mv[48];       // [tt][r]
    const int tid = threadIdx.x;
    const int n   = blockIdx.x >> 4;   // 16 segments per n
    const int seg = blockIdx.x & 15;
    const int t0  = seg * 3;
    const float* xbn = xbar + (size_t)n * C_ * T_;
    #pragma unroll
    for (int tt = 0; tt < 3; ++tt)
        xb[tid * 3 + tt] = xbn[tid * T_ + t0 + tt];
    __syncthreads();
    if (tid < 48) {  // squeeze conv + BN on the v-means
        const int tt = tid >> 4, r = tid & 15;
        float acc = 0.f;
        for (int c = 0; c < C_; ++c) acc += xb[c * 3 + tt] * wsq[r * C_ + c];
        float sc = gamma[r] * rsqrtf(rvar[r] + 1e-5f);
        float sh = beta[r] - rmean[r] * sc;
        ybn[tt * 16 + r] = (acc + bsq[r]) * sc + sh;
    }
    __syncthreads();
    if (tid < 48) {  // conv1
        const int tt = tid >> 4, s = tid & 15;
        float acc = bc1[s];
        #pragma unroll
        for (int r = 0; r < 16; ++r) acc += ybn[tt * 16 + r] * wc1[s * 16 + r];
        y1[tt * 16 + s] = acc;
    }
    __syncthreads();
    if (tid < 48) {  // temporal diff; last frame of each segment -> 0
        const int tt = tid >> 4, r = tid & 15;
        mv[tid] = (tt < 2) ? (y1[(tt + 1) * 16 + r] - ybn[tt * 16 + r]) : 0.f;
    }
    __syncthreads();
    // expand conv + sigmoid; thread = channel c
    const int c = tid;
    float w[16];
    #pragma unroll
    for (int r = 0; r < 16; ++r) w[r] = wex[c * 16 + r];
    const float be = bex[c];
    float* gout = gate + ((size_t)n * C_ + c) * T_ + t0;
    #pragma unroll
    for (int tt = 0; tt < 3; ++tt) {
        float a = be;
        #pragma unroll
        for (int r = 0; r < 16; ++r) a += mv[tt * 16 + r] * w[r];
        gout[tt] = 1.f / (1.f + expf(-a));
    }
}

// K3: out[i] = x[i] * gate[i/25], float4 grid-stride.
__global__ __launch_bounds__(256) void k_apply(const float* __restrict__ x,
                                               const float* __restrict__ gate,
                                               float* __restrict__ out) {
    const float4* x4 = (const float4*)x;
    float4* o4 = (float4*)out;
    const unsigned total4 = (unsigned)(N_ * C_ * T_ * V_) / 4u;  // 9,830,400
    for (unsigned i4 = blockIdx.x * 256u + threadIdx.x; i4 < total4;
         i4 += gridDim.x * 256u) {
        float4 xv = x4[i4];
        unsigned i0 = i4 * 4u;
        unsigned r0 = i0 / 25u;
        unsigned j  = i0 - r0 * 25u;
        unsigned r3 = (j + 3u >= 25u) ? r0 + 1u : r0;
        float g0 = gate[r0];
        float g3 = gate[r3];
        float4 ov;
        ov.x = xv.x * g0;
        ov.y = xv.y * ((j + 1u < 25u) ? g0 : g3);
        ov.z = xv.z * ((j + 2u < 25u) ? g0 : g3);
        ov.w = xv.w * ((j + 3u < 25u) ? g0 : g3);
        o4[i4] = ov;
    }
}

extern "C" void kernel_launch(void* const* d_in, const int* in_sizes, int n_in,
                              void* d_out, int out_size, void* d_ws, size_t ws_size,
                              hipStream_t stream) {
    const float* x     = (const float*)d_in[0];
    const float* wsq   = (const float*)d_in[1];
    const float* bsq   = (const float*)d_in[2];
    const float* gamma = (const float*)d_in[3];
    const float* beta  = (const float*)d_in[4];
    const float* rmean = (const float*)d_in[5];
    const float* rvar  = (const float*)d_in[6];
    const float* wc1   = (const float*)d_in[7];
    const float* bc1   = (const float*)d_in[8];
    const float* wex   = (const float*)d_in[9];
    const float* bex   = (const float*)d_in[10];

    float* xbar = (float*)d_ws;                       // N*C*T floats = 6.29 MB
    float* gate = xbar + (size_t)N_ * C_ * T_;        // N*C*T floats = 6.29 MB

    const int rows = N_ * C_ * T_;                    // 1,572,864
    k_rowmean<<<rows / 256, 256, 0, stream>>>(x, xbar);
    k_gate<<<N_ * (T_ / 3), 256, 0, stream>>>(xbar, wsq, bsq, gamma, beta,
                                              rmean, rvar, wc1, bc1, wex, bex, gate);
    k_apply<<<4096, 256, 0, stream>>>(x, gate, (float*)d_out);
}